// Round 26
// baseline (143.597 us; speedup 1.0000x reference)
//
#include <hip/hip_runtime.h>

#define TT 256
#define BB 512
#define DD 128
#define HH 50
#define KK 5
#define AA 4
#define NROW 131072
#define GST 52           // g row stride (16B-aligned float4 slots)
#define CXS2 276         // ctx_lT row stride (f16)
#define KQS2 20          // kq_l row stride (f16)

#define R50(X) X(0) X(1) X(2) X(3) X(4) X(5) X(6) X(7) X(8) X(9) \
  X(10) X(11) X(12) X(13) X(14) X(15) X(16) X(17) X(18) X(19) \
  X(20) X(21) X(22) X(23) X(24) X(25) X(26) X(27) X(28) X(29) \
  X(30) X(31) X(32) X(33) X(34) X(35) X(36) X(37) X(38) X(39) \
  X(40) X(41) X(42) X(43) X(44) X(45) X(46) X(47) X(48) X(49)

typedef _Float16 half4 __attribute__((ext_vector_type(4)));
typedef float f32x4 __attribute__((ext_vector_type(4)));

// ---------------- K0: weight prep ----------------
__global__ void k0_prep(const float* __restrict__ W_in,
                        const float* __restrict__ W_ctx,
                        const float* __restrict__ W_key,
                        const float* __restrict__ W_q,
                        const float* __restrict__ b_key,
                        const float* __restrict__ b_q,
                        float* __restrict__ WHT,
                        float* __restrict__ WK2T, float* __restrict__ bias2) {
  int i = blockIdx.x * 256 + threadIdx.x;
  if (i < HH * 52) {
    int j = i / 52, h = i % 52;
    WHT[i] = (h < HH) ? W_ctx[h * (2 * HH) + HH + j] : 0.f;
  }
  if (i < HH * 64) {
    int j = i >> 6, l = i & 63;
    float v = 0.f;
    if (l < HH) v = W_ctx[l * (2 * HH) + j];
    else if (l < HH + KK) v = W_key[(l - HH) * HH + j];
    else if (l < HH + 2 * KK) v = W_q[(l - HH - KK) * HH + j];
    WK2T[i] = v;
  }
  if (i < 64) {
    float bv = 0.f;
    if (i >= HH && i < HH + KK) bv = b_key[i - HH];
    else if (i >= HH + KK && i < HH + 2 * KK) bv = b_q[i - HH - KK];
    bias2[i] = bv;
  }
}

// ---------------- K1 (MFMA, fused): g = relu(x@W_in^T+b_in)@Wh^T + b_ctx ---
__global__ __launch_bounds__(256, 2) void k1_mfma(
    const float* __restrict__ x, const float* __restrict__ W_in,
    const float* __restrict__ WHT, const float* __restrict__ b_in,
    const float* __restrict__ b_ctx, float* __restrict__ g) {
  const int lane = threadIdx.x & 63;
  const int wave = threadIdx.x >> 6;
  const int lrow = lane & 15, lgrp = lane >> 4;

#define WA1D(m, kk)                                                     \
  half4 wa1_##m##_##kk;                                                 \
  {                                                                     \
    const int hh = 16 * (m) + lrow;                                     \
    const int j0 = 16 * (kk) + 4 * lgrp;                                \
    const bool v = (hh < HH);                                           \
    const float* p = W_in + (size_t)(v ? hh : 0) * DD + j0;             \
    wa1_##m##_##kk[0] = (_Float16)(v ? p[0] : 0.f);                     \
    wa1_##m##_##kk[1] = (_Float16)(v ? p[1] : 0.f);                     \
    wa1_##m##_##kk[2] = (_Float16)(v ? p[2] : 0.f);                     \
    wa1_##m##_##kk[3] = (_Float16)(v ? p[3] : 0.f);                     \
  }
  WA1D(0, 0) WA1D(0, 1) WA1D(0, 2) WA1D(0, 3)
  WA1D(0, 4) WA1D(0, 5) WA1D(0, 6) WA1D(0, 7)
  WA1D(1, 0) WA1D(1, 1) WA1D(1, 2) WA1D(1, 3)
  WA1D(1, 4) WA1D(1, 5) WA1D(1, 6) WA1D(1, 7)
  WA1D(2, 0) WA1D(2, 1) WA1D(2, 2) WA1D(2, 3)
  WA1D(2, 4) WA1D(2, 5) WA1D(2, 6) WA1D(2, 7)
  WA1D(3, 0) WA1D(3, 1) WA1D(3, 2) WA1D(3, 3)
  WA1D(3, 4) WA1D(3, 5) WA1D(3, 6) WA1D(3, 7)

#define WA2D(m, kk)                                                     \
  half4 wa2_##m##_##kk;                                                 \
  {                                                                     \
    const int gg = 16 * (m) + lrow;                                     \
    const int h0 = 16 * (kk) + 4 * lgrp;                                \
    wa2_##m##_##kk[0] = (_Float16)((gg < HH && h0 + 0 < HH) ? WHT[(h0 + 0) * 52 + gg] : 0.f); \
    wa2_##m##_##kk[1] = (_Float16)((gg < HH && h0 + 1 < HH) ? WHT[(h0 + 1) * 52 + gg] : 0.f); \
    wa2_##m##_##kk[2] = (_Float16)((gg < HH && h0 + 2 < HH) ? WHT[(h0 + 2) * 52 + gg] : 0.f); \
    wa2_##m##_##kk[3] = (_Float16)((gg < HH && h0 + 3 < HH) ? WHT[(h0 + 3) * 52 + gg] : 0.f); \
  }
  WA2D(0, 0) WA2D(0, 1) WA2D(0, 2) WA2D(0, 3)
  WA2D(1, 0) WA2D(1, 1) WA2D(1, 2) WA2D(1, 3)
  WA2D(2, 0) WA2D(2, 1) WA2D(2, 2) WA2D(2, 3)
  WA2D(3, 0) WA2D(3, 1) WA2D(3, 2) WA2D(3, 3)

#define BDEF(m, r)                                                      \
  const float bin_##m##_##r =                                           \
      (16 * (m) + 4 * lgrp + (r) < HH) ? b_in[16 * (m) + 4 * lgrp + (r)] : 0.f; \
  const float bct_##m##_##r =                                           \
      (16 * (m) + 4 * lgrp + (r) < HH) ? b_ctx[16 * (m) + 4 * lgrp + (r)] : 0.f;
  BDEF(0, 0) BDEF(0, 1) BDEF(0, 2) BDEF(0, 3)
  BDEF(1, 0) BDEF(1, 1) BDEF(1, 2) BDEF(1, 3)
  BDEF(2, 0) BDEF(2, 1) BDEF(2, 2) BDEF(2, 3)
  BDEF(3, 0) BDEF(3, 1) BDEF(3, 2) BDEF(3, 3)

  const f32x4 zf = {0.f, 0.f, 0.f, 0.f};

#pragma unroll 1
  for (int it = 0; it < 4; ++it) {
    const int tile = (blockIdx.x * 4 + wave) * 4 + it;
    const int row = tile * 16 + lrow;
    const float* __restrict__ xr = x + (size_t)row * DD + 4 * lgrp;

#define XLD(kk)                                                         \
  half4 xb##kk;                                                         \
  {                                                                     \
    const float4 xv = *reinterpret_cast<const float4*>(xr + 16 * kk);   \
    xb##kk[0] = (_Float16)xv.x;                                         \
    xb##kk[1] = (_Float16)xv.y;                                         \
    xb##kk[2] = (_Float16)xv.z;                                         \
    xb##kk[3] = (_Float16)xv.w;                                         \
  }
    XLD(0) XLD(1) XLD(2) XLD(3) XLD(4) XLD(5) XLD(6) XLD(7)

    f32x4 d10 = zf, d11 = zf, d12 = zf, d13 = zf;
#define MM1(kk)                                                              \
  d10 = __builtin_amdgcn_mfma_f32_16x16x16f16(wa1_0_##kk, xb##kk, d10, 0, 0, 0); \
  d11 = __builtin_amdgcn_mfma_f32_16x16x16f16(wa1_1_##kk, xb##kk, d11, 0, 0, 0); \
  d12 = __builtin_amdgcn_mfma_f32_16x16x16f16(wa1_2_##kk, xb##kk, d12, 0, 0, 0); \
  d13 = __builtin_amdgcn_mfma_f32_16x16x16f16(wa1_3_##kk, xb##kk, d13, 0, 0, 0);
    MM1(0) MM1(1) MM1(2) MM1(3) MM1(4) MM1(5) MM1(6) MM1(7)

#define HBD(k)                                                    \
  half4 hb##k;                                                    \
  hb##k[0] = (_Float16)fmaxf(d1##k[0] + bin_##k##_0, 0.f);        \
  hb##k[1] = (_Float16)fmaxf(d1##k[1] + bin_##k##_1, 0.f);        \
  hb##k[2] = (_Float16)fmaxf(d1##k[2] + bin_##k##_2, 0.f);        \
  hb##k[3] = (_Float16)fmaxf(d1##k[3] + bin_##k##_3, 0.f);
    HBD(0) HBD(1) HBD(2) HBD(3)

    f32x4 d20 = zf, d21 = zf, d22 = zf, d23 = zf;
#define MM2(kk)                                                              \
  d20 = __builtin_amdgcn_mfma_f32_16x16x16f16(wa2_0_##kk, hb##kk, d20, 0, 0, 0); \
  d21 = __builtin_amdgcn_mfma_f32_16x16x16f16(wa2_1_##kk, hb##kk, d21, 0, 0, 0); \
  d22 = __builtin_amdgcn_mfma_f32_16x16x16f16(wa2_2_##kk, hb##kk, d22, 0, 0, 0); \
  d23 = __builtin_amdgcn_mfma_f32_16x16x16f16(wa2_3_##kk, hb##kk, d23, 0, 0, 0);
    MM2(0) MM2(1) MM2(2) MM2(3)

    float* __restrict__ gr =
        g + ((size_t)(row & (BB - 1)) * TT + (row >> 9)) * GST;
    *reinterpret_cast<float4*>(gr + 4 * lgrp) =
        make_float4(d20[0] + bct_0_0, d20[1] + bct_0_1, d20[2] + bct_0_2,
                    d20[3] + bct_0_3);
    *reinterpret_cast<float4*>(gr + 16 + 4 * lgrp) =
        make_float4(d21[0] + bct_1_0, d21[1] + bct_1_1, d21[2] + bct_1_2,
                    d21[3] + bct_1_3);
    *reinterpret_cast<float4*>(gr + 32 + 4 * lgrp) =
        make_float4(d22[0] + bct_2_0, d22[1] + bct_2_1, d22[2] + bct_2_2,
                    d22[3] + bct_2_3);
    if (lgrp == 0) {
      *reinterpret_cast<float4*>(gr + 48) =
          make_float4(d23[0] + bct_3_0, d23[1] + bct_3_1, 0.f, 0.f);
    }
  }
}

// ---------------- K23: fused recurrence + attention (512 blocks x 2 waves) -
// R25 layouts/protocol verbatim. R26: block shrunk to 128 threads — 1
// producer + 1 consumer wave. At 2 blocks/CU -> 4 waves/CU = ONE wave per
// SIMD: the serial chain gets a private SIMD (no issue-resume penalty from
// co-resident waves, the mechanism behind the fused chain's +260 cy/step).
// Single consumer handles all 16 tiles (~120K cy work << 264K window).
__global__ __launch_bounds__(128, 2) void k23_fused(
    const float* __restrict__ g, const float* __restrict__ WK2T,
    const float* __restrict__ bias2, const float* __restrict__ fc,
    const float* __restrict__ W_act, const float* __restrict__ b_act,
    float* __restrict__ out) {
  __shared__ _Float16 ctx_lT[64 * CXS2];  // [h][s], h>=50 rows stay 0
  __shared__ _Float16 kq_l[272 * KQS2];   // [s][slot]: k@0-4, q@8-12, else 0
  __shared__ __align__(16) float c_lds[64];
  __shared__ int prog;

  const int tid = threadIdx.x;
  const int b = blockIdx.x;
  const int wv = tid >> 6;
  const int lane = tid & 63;

  for (int i = tid; i < 64 * CXS2; i += 128) ctx_lT[i] = (_Float16)0.f;
  for (int i = tid; i < 272 * KQS2; i += 128) kq_l[i] = (_Float16)0.f;
  if (tid == 0) prog = 0;
  __syncthreads();

  if (wv == 0) {
    // ================= recurrence (wave 0), HIGH PRIORITY =================
    __builtin_amdgcn_s_setprio(3);
#define WDECL(j)                            \
  float w##j = WK2T[(j) * 64 + lane];       \
  asm volatile("" : "+v"(w##j));
    R50(WDECL)
    const float wz = 0.f;
    const float bias = bias2[lane];

    const float c0v = (lane < HH) ? fc[lane] : 0.f;
    c_lds[lane] = (lane < HH) ? c0v : 0.f;
    if (lane < HH) ctx_lT[lane * CXS2 + 0] = (_Float16)c0v;

    const int gslot = (lane < GST) ? lane : (GST - 1);
    const float* __restrict__ gbp = g + (size_t)b * TT * GST + gslot;
    float gq0 = gbp[0 * GST];
    float gq1 = gbp[1 * GST];
    float gq2 = gbp[2 * GST];
    float gq3 = gbp[3 * GST];

    const bool iskq = (lane >= HH && lane < HH + 2 * KK);
    const int kslot = iskq ? ((lane < HH + KK) ? lane - HH : lane - HH - KK + 8)
                           : 0;

#define KQ(J, wa, wb, wc, wd)                                            \
  {                                                                      \
    const float4 cq = *reinterpret_cast<const float4*>(&c_lds[J]);       \
    acc0 = fmaf(wa, cq.x, acc0);                                         \
    acc1 = fmaf(wb, cq.y, acc1);                                         \
    acc2 = fmaf(wc, cq.z, acc2);                                         \
    acc3 = fmaf(wd, cq.w, acc3);                                         \
  }
#define DOT50R                                                           \
  float acc0 = 0.f, acc1 = 0.f, acc2 = 0.f, acc3 = 0.f;                  \
  KQ(0, w0, w1, w2, w3) KQ(4, w4, w5, w6, w7)                            \
  KQ(8, w8, w9, w10, w11) KQ(12, w12, w13, w14, w15)                     \
  KQ(16, w16, w17, w18, w19) KQ(20, w20, w21, w22, w23)                  \
  KQ(24, w24, w25, w26, w27) KQ(28, w28, w29, w30, w31)                  \
  KQ(32, w32, w33, w34, w35) KQ(36, w36, w37, w38, w39)                  \
  KQ(40, w40, w41, w42, w43) KQ(44, w44, w45, w46, w47)                  \
  KQ(48, w48, w49, wz, wz)                                               \
  const float acc = (acc0 + acc1) + (acc2 + acc3);

#define BODYF(RR, GQ)                                                    \
  {                                                                      \
    const int t = tg4 + RR;                                              \
    DOT50R                                                               \
    if (iskq) kq_l[t * KQS2 + kslot] = (_Float16)(acc + bias);           \
    const float cn = fmaxf(acc + GQ, 0.f);                               \
    GQ = gbp[(size_t)min(t + 4, TT - 1) * GST];                          \
    if (lane < HH) {                                                     \
      ctx_lT[lane * CXS2 + (t + 1)] = (_Float16)cn;                      \
      c_lds[lane] = cn;                                                  \
    }                                                                    \
  }

#pragma unroll 1
    for (int tg4 = 0; tg4 < TT; tg4 += 4) {
      BODYF(0, gq0) BODYF(1, gq1) BODYF(2, gq2) BODYF(3, gq3)
      if (tg4 & 4) {  // every 8 steps
        asm volatile("" ::: "memory");
        if (lane == 0) *((volatile int*)&prog) = tg4 + 4;
      }
    }

    {  // tail: key/q of c_TT at index TT (=256)
      DOT50R
      if (iskq) kq_l[TT * KQS2 + kslot] = (_Float16)(acc + bias);
    }
    asm volatile("" ::: "memory");
    __builtin_amdgcn_s_setprio(0);
    if (lane == 0) *((volatile int*)&prog) = 257;

  } else {
    // ================= attention (wave 1), all 16 tiles ===================
    const int lrow = lane & 15, lgrp = lane >> 4;
    const f32x4 zf = {0.f, 0.f, 0.f, 0.f};

#define WACT(a, ht)                                                     \
  const float wa_##a##_##ht =                                           \
      (lrow + 16 * (ht) < HH) ? W_act[(a)*HH + lrow + 16 * (ht)] : 0.f;
    WACT(0, 0) WACT(0, 1) WACT(0, 2) WACT(0, 3)
    WACT(1, 0) WACT(1, 1) WACT(1, 2) WACT(1, 3)
    WACT(2, 0) WACT(2, 1) WACT(2, 2) WACT(2, 3)
    WACT(3, 0) WACT(3, 1) WACT(3, 2) WACT(3, 3)
    const float ba0 = b_act[0], ba1 = b_act[1];
    const float ba2 = b_act[2], ba3 = b_act[3];

#pragma unroll 1
    for (int k = 0; k < 16; ++k) {
      const int tw = k * 16;
      const int need = (tw + 17 > 257) ? 257 : (tw + 17);
      while (*((volatile int*)&prog) < need) __builtin_amdgcn_s_sleep(32);
      asm volatile("" ::: "memory");

      half4 qf = {(_Float16)0.f, (_Float16)0.f, (_Float16)0.f, (_Float16)0.f};
      if (lgrp < 3)
        qf = *reinterpret_cast<const half4*>(
            &kq_l[(tw + lrow + 1) * KQS2 + 8 + 4 * lgrp]);

      f32x4 oa0 = zf, oa1 = zf, oa2 = zf, oa3 = zf;
      float su = 0.f;

#pragma unroll 1
      for (int sb = 0; sb <= tw + 16; sb += 16) {
        const half4 kf = *reinterpret_cast<const half4*>(
            &kq_l[(sb + lrow) * KQS2 + 4 * lgrp]);

        const f32x4 sc =
            __builtin_amdgcn_mfma_f32_16x16x16f16(kf, qf, zf, 0, 0, 0);

        half4 pa;
#pragma unroll
        for (int r = 0; r < 4; ++r) {
          const int s = sb + 4 * lgrp + r;
          const float p = (s <= tw + lrow + 1) ? __expf(sc[r]) : 0.f;
          su += p;
          pa[r] = (_Float16)p;
        }

        const int vb = sb + 4 * lgrp;
#define PVF(HT, ACC)                                                      \
  {                                                                       \
    const half4 vf = *reinterpret_cast<const half4*>(                     \
        &ctx_lT[(lrow + 16 * HT) * CXS2 + vb]);                           \
    ACC = __builtin_amdgcn_mfma_f32_16x16x16f16(pa, vf, ACC, 0, 0, 0);    \
  }
        PVF(0, oa0) PVF(1, oa1) PVF(2, oa2) PVF(3, oa3)
      }

      su += __shfl_xor(su, 16, 64);
      su += __shfl_xor(su, 32, 64);

#define PTC(r)                                                                 \
  float pt##r##_0 = oa0[r] * wa_0_0 + oa1[r] * wa_0_1 + oa2[r] * wa_0_2 +      \
                    oa3[r] * wa_0_3;                                           \
  float pt##r##_1 = oa0[r] * wa_1_0 + oa1[r] * wa_1_1 + oa2[r] * wa_1_2 +      \
                    oa3[r] * wa_1_3;                                           \
  float pt##r##_2 = oa0[r] * wa_2_0 + oa1[r] * wa_2_1 + oa2[r] * wa_2_2 +      \
                    oa3[r] * wa_2_3;                                           \
  float pt##r##_3 = oa0[r] * wa_3_0 + oa1[r] * wa_3_1 + oa2[r] * wa_3_2 +      \
                    oa3[r] * wa_3_3;
      PTC(0) PTC(1) PTC(2) PTC(3)
#define REDX(v)                 \
  v += __shfl_xor(v, 1, 64);    \
  v += __shfl_xor(v, 2, 64);    \
  v += __shfl_xor(v, 4, 64);    \
  v += __shfl_xor(v, 8, 64);
      REDX(pt0_0) REDX(pt0_1) REDX(pt0_2) REDX(pt0_3)
      REDX(pt1_0) REDX(pt1_1) REDX(pt1_2) REDX(pt1_3)
      REDX(pt2_0) REDX(pt2_1) REDX(pt2_2) REDX(pt2_3)
      REDX(pt3_0) REDX(pt3_1) REDX(pt3_2) REDX(pt3_3)

#define EPI(r)                                                            \
  {                                                                       \
    const float sur = __shfl(su, 4 * lgrp + (r), 64);                     \
    if (lrow == 0) {                                                      \
      const float inv = 1.f / sur;                                        \
      const int t = tw + 4 * lgrp + (r);                                  \
      *reinterpret_cast<float4*>(out + ((size_t)t * BB + b) * AA) =       \
          make_float4(fmaf(pt##r##_0, inv, ba0), fmaf(pt##r##_1, inv, ba1), \
                      fmaf(pt##r##_2, inv, ba2), fmaf(pt##r##_3, inv, ba3)); \
    }                                                                     \
  }
      EPI(0) EPI(1) EPI(2) EPI(3)
    }
  }
}

extern "C" void kernel_launch(void* const* d_in, const int* in_sizes, int n_in,
                              void* d_out, int out_size, void* d_ws,
                              size_t ws_size, hipStream_t stream) {
  const float* x = (const float*)d_in[0];
  const float* W_in = (const float*)d_in[1];
  const float* b_in = (const float*)d_in[2];
  const float* W_ctx = (const float*)d_in[3];
  const float* b_ctx = (const float*)d_in[4];
  const float* W_key = (const float*)d_in[5];
  const float* b_key = (const float*)d_in[6];
  const float* W_q = (const float*)d_in[7];
  const float* b_q = (const float*)d_in[8];
  const float* fc = (const float*)d_in[9];
  const float* W_act = (const float*)d_in[10];
  const float* b_act = (const float*)d_in[11];
  float* out = (float*)d_out;
  float* ws = (float*)d_ws;

  float* WHT = ws;                                 // 50*52
  float* WK2T = ws + 4096;                         // 50*64
  float* bias2 = ws + 8128;                        // 64
  float* g = ws + 8192;                            // 131072*52
  // total ~27 MB

  hipLaunchKernelGGL(k0_prep, dim3(26), dim3(256), 0, stream, W_in, W_ctx,
                     W_key, W_q, b_key, b_q, WHT, WK2T, bias2);
  hipLaunchKernelGGL(k1_mfma, dim3(512), dim3(256), 0, stream, x, W_in, WHT,
                     b_in, b_ctx, g);
  hipLaunchKernelGGL(k23_fused, dim3(512), dim3(128), 0, stream, g, WK2T,
                     bias2, fc, W_act, b_act, out);
}